// Round 1
// 605.211 us; speedup vs baseline: 1.1433x; 1.1433x over previous
//
#include <hip/hip_runtime.h>
#include <stdint.h>
#include <math.h>

#define USER_N 100000
#define NODE_N 150000
#define DD 64
#define NNZE 2400000
#define BB 4096
#define NLV 3
#define LF 32
#define HALF_SZ 196608u  /* (3*4096*32)/2 */
#define NTILE 586        /* ceil(150000/256) */
#define NSUB 8           /* per-tile sub-segments, one per physical XCD */
#define SCAP 1024        /* capacity per (tile,xcd) segment; mean 512 */
#define EPB 4096         /* edges per scatter block */

typedef __attribute__((ext_vector_type(8))) short bf16x8;
typedef __attribute__((ext_vector_type(4))) float f32x4;
typedef __attribute__((ext_vector_type(2))) float f32x2;

// HW_REG_XCC_ID: id=20, offset=0, width=32 -> imm = 20 | (31<<11)
#define XCC_ID_IMM 63508

// ---------------- threefry2x32 (JAX original mode) ----------------
__host__ __device__ inline void tf_block(uint32_t k0, uint32_t k1, uint32_t& x0, uint32_t& x1) {
  uint32_t ks[3] = {k0, k1, k0 ^ k1 ^ 0x1BD11BDAu};
  x0 += ks[0]; x1 += ks[1];
  const int R0[4] = {13, 15, 26, 6};
  const int R1[4] = {17, 29, 16, 24};
#pragma unroll
  for (int i = 0; i < 5; ++i) {
    const int* R = (i & 1) ? R1 : R0;
#pragma unroll
    for (int j = 0; j < 4; ++j) {
      x0 += x1;
      x1 = (x1 << R[j]) | (x1 >> (32 - R[j]));
      x1 ^= x0;
    }
    x0 += ks[(i + 1) % 3];
    x1 += ks[(i + 2) % 3] + (uint32_t)(i + 1);
  }
}

__device__ inline float tf_uniform(uint32_t ka, uint32_t kb, uint32_t m) {
  uint32_t x0, x1;
  bool first = m < HALF_SZ;
  if (first) { x0 = m; x1 = m + HALF_SZ; } else { x0 = m - HALF_SZ; x1 = m; }
  tf_block(ka, kb, x0, x1);
  uint32_t bits = first ? x0 : x1;
  return __uint_as_float((bits >> 9) | 0x3f800000u) - 1.0f;
}

// bf16 round-to-nearest-even
__device__ inline unsigned short f2bf(float x) {
  uint32_t b = __float_as_uint(x);
  return (unsigned short)((b + 0x7FFFu + ((b >> 16) & 1u)) >> 16);
}

// fp8 e4m3 (HW cvt, OCP on gfx950): one byte from a float
__device__ inline unsigned char f2fp8(float x) {
  return (unsigned char)(__builtin_amdgcn_cvt_pk_fp8_f32(x, x, 0, false) & 0xFF);
}

// decode 4 packed e4m3 bytes -> 4 floats, then acc += v * row4
__device__ inline void fp8_fma(float4& acc, uint2 rec, uint32_t wrd) {
  float vv = __uint_as_float(rec.y);
  f32x2 lo = __builtin_amdgcn_cvt_pk_f32_fp8((int)wrd, false);
  f32x2 hi = __builtin_amdgcn_cvt_pk_f32_fp8((int)wrd, true);
  acc.x = fmaf(vv, lo.x, acc.x);
  acc.y = fmaf(vv, lo.y, acc.y);
  acc.z = fmaf(vv, hi.x, acc.z);
  acc.w = fmaf(vv, hi.y, acc.w);
}

// ---------------- kernels ----------------
// init: fp8 mirror of ego for the spmm gathers (4 dims -> 1 uint per thread)
__global__ __launch_bounds__(256) void k_init(const float* __restrict__ ego,
                                              uint32_t* __restrict__ E8) {
  int i = blockIdx.x * 256 + threadIdx.x;  // float4 index
  float4 v = ((const float4*)ego)[i];
  int w01 = __builtin_amdgcn_cvt_pk_fp8_f32(v.x, v.y, 0, false);
  int w = __builtin_amdgcn_cvt_pk_fp8_f32(v.z, v.w, w01, true);
  E8[i] = (uint32_t)w;
}

// Block-aggregated scatter (r10): LDS histogram over 586 tiles -> ONE global
// atomic per (tile, block) reserving a contiguous range in this XCD's segment.
__global__ __launch_bounds__(256) void k_scatter_t(const int* __restrict__ rows,
                                                   const int* __restrict__ cols,
                                                   const float* __restrict__ vals,
                                                   int* __restrict__ cursor,
                                                   uint2* __restrict__ sedge_r) {
  __shared__ int cnt[NTILE];
  __shared__ int curs[NTILE];
  int t = threadIdx.x;
  for (int i = t; i < NTILE; i += 256) cnt[i] = 0;
  __syncthreads();
  int r[16];
  int ebase = blockIdx.x * EPB;
#pragma unroll
  for (int j = 0; j < 16; ++j) {
    int e = ebase + j * 256 + t;
    r[j] = (e < NNZE) ? rows[e] : -1;
    if (r[j] >= 0) atomicAdd(&cnt[r[j] >> 8], 1);
  }
  __syncthreads();
  unsigned myx = __builtin_amdgcn_s_getreg(XCC_ID_IMM) & (NSUB - 1);
  for (int i = t; i < NTILE; i += 256) {
    int c = cnt[i];
    curs[i] = c ? atomicAdd(&cursor[(i * NSUB + (int)myx) * 16], c) : 0;
  }
  __syncthreads();
#pragma unroll
  for (int j = 0; j < 16; ++j) {
    if (r[j] < 0) continue;
    int e = ebase + j * 256 + t;
    int tile = r[j] >> 8;
    uint2 rec = make_uint2((uint32_t)cols[e] | ((uint32_t)(r[j] & 255) << 18),
                           __float_as_uint(vals[e]));
    int p = atomicAdd(&curs[tile], 1);
    if (p < SCAP) {
      sedge_r[(size_t)(tile * NSUB + (int)myx) * SCAP + p] = rec;
    } else {
#pragma unroll 1
      for (int att = 1; att < NSUB; ++att) {
        int seg = tile * NSUB + (int)((myx + att) & (NSUB - 1));
        int p2 = atomicAdd(&cursor[seg * 16], 1);
        if (p2 < SCAP) { sedge_r[(size_t)seg * SCAP + p2] = rec; break; }
      }
    }
  }
}

// tiny scan over 586 tile totals (from cursors) -> out_base for sorted CSR
__global__ __launch_bounds__(1024) void k_scan586(const int* __restrict__ cursor,
                                                  int* __restrict__ out_base,
                                                  int* __restrict__ row_start) {
  __shared__ int buf[1024];
  int t = threadIdx.x;
  int tot = 0;
  if (t < NTILE) {
#pragma unroll
    for (int x = 0; x < NSUB; ++x) {
      int c = cursor[(t * NSUB + x) * 16];
      tot += (c < SCAP) ? c : SCAP;
    }
  }
  buf[t] = tot;
  __syncthreads();
  for (int off = 1; off < 1024; off <<= 1) {
    int add = (t >= off) ? buf[t - off] : 0;
    __syncthreads();
    buf[t] += add;
    __syncthreads();
  }
  if (t < NTILE) out_base[t] = buf[t] - tot;  // exclusive
  if (t == 0) row_start[NODE_N] = NNZE;
}

// per-tile 256-bin counting sort: drains the 8 sub-segments -> row-sorted CSR.
__global__ __launch_bounds__(256) void k_sort_t(const uint2* __restrict__ sedge_r,
                                                const int* __restrict__ cursor,
                                                const int* __restrict__ out_base,
                                                uint2* __restrict__ sedge,
                                                int* __restrict__ row_start) {
  __shared__ int hist[256], buf[256], curs[256];
  int t = threadIdx.x;
  int tile = blockIdx.x;
  int obase = out_base[tile];
  hist[t] = 0;
  __syncthreads();
#pragma unroll 1
  for (int x = 0; x < NSUB; ++x) {
    int seg = tile * NSUB + x;
    int cnt = cursor[seg * 16];
    if (cnt > SCAP) cnt = SCAP;
    const uint2* sp = sedge_r + (size_t)seg * SCAP;
    for (int i = t; i < cnt; i += 256)
      atomicAdd(&hist[sp[i].x >> 18], 1);
  }
  __syncthreads();
  int v = hist[t];
  buf[t] = v;
  __syncthreads();
  for (int off = 1; off < 256; off <<= 1) {
    int add = (t >= off) ? buf[t - off] : 0;
    __syncthreads();
    buf[t] += add;
    __syncthreads();
  }
  int excl = buf[t] - v;
  curs[t] = excl;
  int row = tile * 256 + t;
  if (row < NODE_N) row_start[row] = obase + excl;
  __syncthreads();
#pragma unroll 1
  for (int x = 0; x < NSUB; ++x) {
    int seg = tile * NSUB + x;
    int cnt = cursor[seg * 16];
    if (cnt > SCAP) cnt = SCAP;
    const uint2* sp = sedge_r + (size_t)seg * SCAP;
    for (int i = t; i < cnt; i += 256) {
      uint2 rec = sp[i];
      int rl = rec.x >> 18;
      int p = atomicAdd(&curs[rl], 1);
      sedge[obase + p] = make_uint2(rec.x & 0x3FFFFu, rec.y);
    }
  }
}

// wave-per-row SpMM over sorted CSR, fp8 E gathers (64B/row — half of r10's
// bf16; the 160MB FETCH was gather fills at a ~2.4TB/s random-access ceiling).
// Epilogue reads its OWN fp8 row (64B) instead of Eprev fp32 (256B, -38.4MB).
__global__ __launch_bounds__(256) void k_spmm(const uint32_t* __restrict__ E8,
                                              const uint2* __restrict__ sedge,
                                              const int* __restrict__ row_start,
                                              unsigned short* __restrict__ side16,
                                              unsigned short* __restrict__ p16) {
  int r = blockIdx.x * 4 + (threadIdx.x >> 6);
  int lane = threadIdx.x & 63;
  int g = lane >> 4;
  int q = lane & 15;
  int rs = row_start[r], re = row_start[r + 1];
  float4 acc = make_float4(0.f, 0.f, 0.f, 0.f);
  int e = rs;
  for (; e + 16 <= re; e += 16) {
    uint2 e0 = sedge[e + g];
    uint2 e1 = sedge[e + 4 + g];
    uint2 e2 = sedge[e + 8 + g];
    uint2 e3 = sedge[e + 12 + g];
    uint32_t a0 = E8[(size_t)e0.x * 16 + q];
    uint32_t a1 = E8[(size_t)e1.x * 16 + q];
    uint32_t a2 = E8[(size_t)e2.x * 16 + q];
    uint32_t a3 = E8[(size_t)e3.x * 16 + q];
    fp8_fma(acc, e0, a0);
    fp8_fma(acc, e1, a1);
    fp8_fma(acc, e2, a2);
    fp8_fma(acc, e3, a3);
  }
  for (; e + 8 <= re; e += 8) {
    uint2 e0 = sedge[e + g];
    uint2 e1 = sedge[e + 4 + g];
    uint32_t a0 = E8[(size_t)e0.x * 16 + q];
    uint32_t a1 = E8[(size_t)e1.x * 16 + q];
    fp8_fma(acc, e0, a0);
    fp8_fma(acc, e1, a1);
  }
  for (; e + 4 <= re; e += 4) {
    uint2 e0 = sedge[e + g];
    uint32_t a0 = E8[(size_t)e0.x * 16 + q];
    fp8_fma(acc, e0, a0);
  }
  for (; e < re; ++e) {
    if (g == (e & 3)) {
      uint2 e0 = sedge[e];
      uint32_t a0 = E8[(size_t)e0.x * 16 + q];
      fp8_fma(acc, e0, a0);
    }
  }
#pragma unroll
  for (int off = 16; off <= 32; off <<= 1) {
    acc.x += __shfl_xor(acc.x, off, 64);
    acc.y += __shfl_xor(acc.y, off, 64);
    acc.z += __shfl_xor(acc.z, off, 64);
    acc.w += __shfl_xor(acc.w, off, 64);
  }
  if (g == 0) {
    uint32_t ew = E8[(size_t)r * 16 + q];
    f32x2 elo = __builtin_amdgcn_cvt_pk_f32_fp8((int)ew, false);
    f32x2 ehi = __builtin_amdgcn_cvt_pk_f32_fp8((int)ew, true);
    ushort4 s16, pp;
    s16.x = f2bf(acc.x); s16.y = f2bf(acc.y); s16.z = f2bf(acc.z); s16.w = f2bf(acc.w);
    pp.x = f2bf(acc.x * elo.x); pp.y = f2bf(acc.y * elo.y);
    pp.z = f2bf(acc.z * ehi.x); pp.w = f2bf(acc.w * ehi.y);
    *(ushort4*)&side16[(size_t)r * DD + q * 4] = s16;
    *(ushort4*)&p16[(size_t)r * DD + q * 4] = pp;
  }
}

// MFMA transform (layouts verified r7/r8): E_out = l2norm(leaky(side@gw+gb)
// + leaky((E.side)@bw+bb)). Writes fp32 Eout (for gather-sum) + fp8 E8 mirror.
__global__ __launch_bounds__(256) void k_transform(const float* __restrict__ gw,
                                                   const float* __restrict__ gb,
                                                   const float* __restrict__ bw,
                                                   const float* __restrict__ bb,
                                                   const unsigned short* __restrict__ side16,
                                                   const unsigned short* __restrict__ p16,
                                                   float* __restrict__ Eout,
                                                   unsigned char* __restrict__ E8b) {
  int t = threadIdx.x;
  int wv = t >> 6, lane = t & 63;
  int n = lane & 15, quad = lane >> 4;
  bf16x8 wg[4][2], wb[4][2];
  float gbl[4], bbl[4];
#pragma unroll
  for (int c = 0; c < 4; ++c) {
    gbl[c] = gb[c * 16 + n];
    bbl[c] = bb[c * 16 + n];
#pragma unroll
    for (int h = 0; h < 2; ++h) {
#pragma unroll
      for (int j = 0; j < 8; ++j) {
        int k = h * 32 + quad * 8 + j;
        wg[c][h][j] = (short)f2bf(gw[k * 64 + c * 16 + n]);
        wb[c][h][j] = (short)f2bf(bw[k * 64 + c * 16 + n]);
      }
    }
  }
  const f32x4 z = {0.f, 0.f, 0.f, 0.f};
  for (int tile = blockIdx.x * 4 + wv; tile < NODE_N / 16; tile += gridDim.x * 4) {
    int i0 = tile * 16;
    bf16x8 as0 = *(const bf16x8*)&side16[(size_t)(i0 + n) * DD + quad * 8];
    bf16x8 as1 = *(const bf16x8*)&side16[(size_t)(i0 + n) * DD + 32 + quad * 8];
    bf16x8 ap0 = *(const bf16x8*)&p16[(size_t)(i0 + n) * DD + quad * 8];
    bf16x8 ap1 = *(const bf16x8*)&p16[(size_t)(i0 + n) * DD + 32 + quad * 8];
    float v[4][4];
    float sq0 = 0.f, sq1 = 0.f, sq2 = 0.f, sq3 = 0.f;
#pragma unroll
    for (int c = 0; c < 4; ++c) {
      f32x4 ag = __builtin_amdgcn_mfma_f32_16x16x32_bf16(as0, wg[c][0], z, 0, 0, 0);
      ag = __builtin_amdgcn_mfma_f32_16x16x32_bf16(as1, wg[c][1], ag, 0, 0, 0);
      f32x4 ab = __builtin_amdgcn_mfma_f32_16x16x32_bf16(ap0, wb[c][0], z, 0, 0, 0);
      ab = __builtin_amdgcn_mfma_f32_16x16x32_bf16(ap1, wb[c][1], ab, 0, 0, 0);
#pragma unroll
      for (int r = 0; r < 4; ++r) {
        float a1 = ag[r] + gbl[c];
        a1 = (a1 > 0.f) ? a1 : 0.01f * a1;
        float a2 = ab[r] + bbl[c];
        a2 = (a2 > 0.f) ? a2 : 0.01f * a2;
        float vv = a1 + a2;
        v[c][r] = vv;
        if (r == 0) sq0 += vv * vv;
        else if (r == 1) sq1 += vv * vv;
        else if (r == 2) sq2 += vv * vv;
        else sq3 += vv * vv;
      }
    }
#pragma unroll
    for (int off = 1; off < 16; off <<= 1) {
      sq0 += __shfl_xor(sq0, off, 64);
      sq1 += __shfl_xor(sq1, off, 64);
      sq2 += __shfl_xor(sq2, off, 64);
      sq3 += __shfl_xor(sq3, off, 64);
    }
    float inv0 = 1.f / fmaxf(sqrtf(sq0), 1e-12f);
    float inv1 = 1.f / fmaxf(sqrtf(sq1), 1e-12f);
    float inv2 = 1.f / fmaxf(sqrtf(sq2), 1e-12f);
    float inv3 = 1.f / fmaxf(sqrtf(sq3), 1e-12f);
#pragma unroll
    for (int c = 0; c < 4; ++c) {
      float vn0 = v[c][0] * inv0;
      float vn1 = v[c][1] * inv1;
      float vn2 = v[c][2] * inv2;
      float vn3 = v[c][3] * inv3;
      size_t o0 = (size_t)(i0 + quad * 4 + 0) * DD + c * 16 + n;
      size_t o1 = o0 + DD, o2 = o1 + DD, o3 = o2 + DD;
      Eout[o0] = vn0; Eout[o1] = vn1; Eout[o2] = vn2; Eout[o3] = vn3;
      E8b[o0] = f2fp8(vn0); E8b[o1] = f2fp8(vn1);
      E8b[o2] = f2fp8(vn2); E8b[o3] = f2fp8(vn3);
    }
  }
}

// gather: Esum = ego + E1 + E2 on just the 8192 batch rows.
__global__ __launch_bounds__(128) void k_gather(const float* __restrict__ ego,
                                                const float* __restrict__ E1,
                                                const float* __restrict__ E2,
                                                const int* __restrict__ uid,
                                                const int* __restrict__ iid,
                                                float* __restrict__ ue, float* __restrict__ ie) {
  int b = blockIdx.x, t = threadIdx.x;
  if (t < 64) {
    size_t o = (size_t)uid[b] * 64 + t;
    ue[(size_t)b * 64 + t] = ego[o] + E1[o] + E2[o];
  } else {
    int d = t - 64;
    size_t o = (size_t)(USER_N + iid[b]) * 64 + d;
    ie[(size_t)b * 64 + d] = ego[o] + E1[o] + E2[o];
  }
}

// Row-blocked encoder (r11): one block = 32 batch rows for fixed (level, side).
// All 256 threads active in all 3 stages; per-thread register accumulators
// (8/32/4) amortize each weight load over 8-32 FMAs and give independent FMA
// chains (ILP). LDS reads are same-address broadcasts (conflict-free).
// Math identical to old k_encoder: bias-first, k-ascending fp32, tanhf.
__global__ __launch_bounds__(256) void k_encoder2(
    const float* __restrict__ ue, const float* __restrict__ ie,
    const float* __restrict__ uh_w, const float* __restrict__ uh_b,
    const float* __restrict__ ud_w1, const float* __restrict__ ud_b1,
    const float* __restrict__ ud_w2, const float* __restrict__ ud_b2,
    const float* __restrict__ ih_w, const float* __restrict__ ih_b,
    const float* __restrict__ id_w1, const float* __restrict__ id_b1,
    const float* __restrict__ id_w2, const float* __restrict__ id_b2,
    float* __restrict__ recs_u, float* __restrict__ recs_i) {
  __shared__ float sx[32][64];
  __shared__ float sr1[32][64];
  __shared__ float st[32][257];   // +1 pad: stage3 reads rows at stride 257
  int t = threadIdx.x;
  int r0 = blockIdx.x * 32;       // 128 row-blocks x 32 rows = 4096
  int l = blockIdx.y;             // level
  int side = blockIdx.z;          // 0 = user, 1 = item
  const float* xin = side ? ie : ue;
  const float* hw = side ? ih_w : uh_w;
  const float* hb = side ? ih_b : uh_b;
  const float* w1 = side ? id_w1 : ud_w1;
  const float* b1 = side ? id_b1 : ud_b1;
  const float* w2 = side ? id_w2 : ud_w2;
  const float* b2 = side ? id_b2 : ud_b2;
  float* recs = side ? recs_i : recs_u;

  {  // load 32 rows of X, coalesced
    const float* src = xin + (size_t)r0 * 64;
#pragma unroll
    for (int j = 0; j < 8; ++j)
      ((float*)sx)[j * 256 + t] = src[j * 256 + t];
  }
  __syncthreads();

  {  // stage1: R1 = tanh(X @ W0 + b0); thread = col c, 8 rows
    int c = t & 63;
    int rg = (t >> 6) * 8;
    const float* W = hw + (size_t)l * 64 * 64;
    float bias = hb[l * 64 + c];
    float a[8];
#pragma unroll
    for (int j = 0; j < 8; ++j) a[j] = bias;
#pragma unroll 2
    for (int k = 0; k < 64; ++k) {
      float w = W[k * 64 + c];
#pragma unroll
      for (int j = 0; j < 8; ++j) a[j] = fmaf(sx[rg + j][k], w, a[j]);
    }
#pragma unroll
    for (int j = 0; j < 8; ++j) sr1[rg + j][c] = tanhf(a[j]);
  }
  __syncthreads();

  {  // stage2: T = tanh(R1 @ W1 + b1); thread = col t, 32 rows
    const float* W = w1 + (size_t)l * 64 * 256;
    float bias = b1[l * 256 + t];
    float a[32];
#pragma unroll
    for (int j = 0; j < 32; ++j) a[j] = bias;
#pragma unroll 2
    for (int k = 0; k < 64; ++k) {
      float w = W[k * 256 + t];
#pragma unroll
      for (int j = 0; j < 32; ++j) a[j] = fmaf(sr1[j][k], w, a[j]);
    }
#pragma unroll
    for (int j = 0; j < 32; ++j) st[j][t] = tanhf(a[j]);
  }
  __syncthreads();

  {  // stage3: recs = T @ W2 + b2; thread = col c, 4 rows
    int c = t & 31;
    int rg = (t >> 5) * 4;
    const float* W = w2 + (size_t)l * 256 * 32;
    float bias = b2[l * 32 + c];
    float a[4];
#pragma unroll
    for (int j = 0; j < 4; ++j) a[j] = bias;
#pragma unroll 4
    for (int k = 0; k < 256; ++k) {
      float w = W[k * 32 + c];
#pragma unroll
      for (int j = 0; j < 4; ++j) a[j] = fmaf(st[rg + j][k], w, a[j]);
    }
#pragma unroll
    for (int j = 0; j < 4; ++j)
      recs[((size_t)l * BB + (r0 + rg + j)) * 32 + c] = a[j];
  }
}

__global__ __launch_bounds__(256) void k_attn(const float* __restrict__ recs,
                                              const float* __restrict__ qw, const float* __restrict__ qb,
                                              const float* __restrict__ kw, const float* __restrict__ kb,
                                              const float* __restrict__ vw, const float* __restrict__ vb,
                                              float* __restrict__ att) {
  int t = threadIdx.x;
  int b = blockIdx.x * 8 + (t >> 5);
  int d = t & 31;
  float x0 = recs[((size_t)0 * BB + b) * 32 + d];
  float x1 = recs[((size_t)1 * BB + b) * 32 + d];
  float x2 = recs[((size_t)2 * BB + b) * 32 + d];
  float q0 = qb[d], q1 = q0, q2 = q0;
  float c0 = kb[d], c1 = c0, c2 = c0;
  float v0 = vb[d], v1 = v0, v2 = v0;
#pragma unroll 4
  for (int kk = 0; kk < 32; ++kk) {
    float xa = __shfl(x0, kk, 32);
    float xb = __shfl(x1, kk, 32);
    float xc = __shfl(x2, kk, 32);
    float wq = qw[kk * 32 + d], wk = kw[kk * 32 + d], wv = vw[kk * 32 + d];
    q0 += xa * wq; q1 += xb * wq; q2 += xc * wq;
    c0 += xa * wk; c1 += xb * wk; c2 += xc * wk;
    v0 += xa * wv; v1 += xb * wv; v2 += xc * wv;
  }
  float qs[3] = {q0, q1, q2}, ks[3] = {c0, c1, c2}, vs[3] = {v0, v1, v2};
  float sc[3][3];
#pragma unroll
  for (int s = 0; s < 3; ++s)
#pragma unroll
    for (int u = 0; u < 3; ++u) {
      float p = qs[s] * ks[u];
#pragma unroll
      for (int off = 16; off; off >>= 1) p += __shfl_xor(p, off, 32);
      sc[s][u] = p * 0.17677669529663687f;  // 1/sqrt(32)
    }
#pragma unroll
  for (int s = 0; s < 3; ++s) {
    float m = fmaxf(sc[s][0], fmaxf(sc[s][1], sc[s][2]));
    float e0 = __expf(sc[s][0] - m), e1 = __expf(sc[s][1] - m), e2 = __expf(sc[s][2] - m);
    float inv = 1.f / (e0 + e1 + e2);
    att[(size_t)b * 96 + s * 32 + d] = (e0 * vs[0] + e1 * vs[1] + e2 * vs[2]) * inv;
  }
}

// noise: emits l2-normalized recs (n1) and perturbed recs (n2) directly as bf16
// for the MFMA ttl kernel; posdot stays fp32-exact.
__global__ __launch_bounds__(256) void k_noise(const float* __restrict__ att_u,
                                               const float* __restrict__ att_i,
                                               uint32_t ku0, uint32_t ku1, uint32_t ki0, uint32_t ki1,
                                               unsigned short* __restrict__ n1b,
                                               unsigned short* __restrict__ n2b,
                                               float* __restrict__ posdot) {
  int t = threadIdx.x;
  int g = blockIdx.x * 8 + (t >> 5);   // [0, 24576)
  int k = t & 31;
  int side = g / (NLV * BB);
  int rem = g - side * (NLV * BB);
  int l = rem >> 12;
  int b = rem & 4095;
  const float* att = side ? att_i : att_u;
  uint32_t ka = side ? ki0 : ku0;
  uint32_t kb = side ? ki1 : ku1;
  float r = att[(size_t)b * 96 + l * 32 + k];
  float ss = r * r;
#pragma unroll
  for (int off = 16; off; off >>= 1) ss += __shfl_xor(ss, off, 32);
  float v1 = r / fmaxf(sqrtf(ss), 1e-12f);
  uint32_t m = ((uint32_t)(l * BB + b)) * 32u + (uint32_t)k;
  float u = tf_uniform(ka, kb, m);
  float us = u * u;
#pragma unroll
  for (int off = 16; off; off >>= 1) us += __shfl_xor(us, off, 32);
  float un = u / fmaxf(sqrtf(us), 1e-12f);
  float sgn = (r > 0.f) ? 1.f : ((r < 0.f) ? -1.f : 0.f);
  float rn = r + sgn * un * 0.1f;
  float s2 = rn * rn;
#pragma unroll
  for (int off = 16; off; off >>= 1) s2 += __shfl_xor(s2, off, 32);
  float v2 = rn / fmaxf(sqrtf(s2), 1e-12f);
  float pd = v1 * v2;
#pragma unroll
  for (int off = 16; off; off >>= 1) pd += __shfl_xor(pd, off, 32);
  size_t o = (size_t)g * 32 + k;
  n1b[o] = f2bf(v1);
  n2b[o] = f2bf(v2);
  if (k == 0) posdot[g] = pd;
}

// ttl via MFMA (layout verified r7): 6 slices of [4096x4096] = n1.n2^T, K=32.
__global__ __launch_bounds__(256) void k_ttl(const unsigned short* __restrict__ n1b,
                                             const unsigned short* __restrict__ n2b,
                                             float* __restrict__ ttl) {
  int t = threadIdx.x;
  int wv = t >> 6, lane = t & 63;
  int sl = blockIdx.x >> 6;            // 6 slices
  int istripe = blockIdx.x & 63;       // 64 stripes of 64 rows
  int i0 = istripe * 64 + wv * 16;
  const unsigned short* ab = n1b + (size_t)sl * BB * 32;
  const unsigned short* bb = n2b + (size_t)sl * BB * 32;
  int m = lane & 15, quad = lane >> 4;
  bf16x8 afrag = *(const bf16x8*)&ab[(size_t)(i0 + m) * 32 + quad * 8];
  float r0a = 0.f, r1a = 0.f, r2a = 0.f, r3a = 0.f;
  f32x4 z = {0.f, 0.f, 0.f, 0.f};
  for (int jt = 0; jt < 256; jt += 4) {
    bf16x8 b0 = *(const bf16x8*)&bb[((size_t)((jt + 0) * 16 + m)) * 32 + quad * 8];
    bf16x8 b1 = *(const bf16x8*)&bb[((size_t)((jt + 1) * 16 + m)) * 32 + quad * 8];
    bf16x8 b2 = *(const bf16x8*)&bb[((size_t)((jt + 2) * 16 + m)) * 32 + quad * 8];
    bf16x8 b3 = *(const bf16x8*)&bb[((size_t)((jt + 3) * 16 + m)) * 32 + quad * 8];
    f32x4 s0 = __builtin_amdgcn_mfma_f32_16x16x32_bf16(afrag, b0, z, 0, 0, 0);
    f32x4 s1 = __builtin_amdgcn_mfma_f32_16x16x32_bf16(afrag, b1, z, 0, 0, 0);
    f32x4 s2 = __builtin_amdgcn_mfma_f32_16x16x32_bf16(afrag, b2, z, 0, 0, 0);
    f32x4 s3 = __builtin_amdgcn_mfma_f32_16x16x32_bf16(afrag, b3, z, 0, 0, 0);
    r0a += __expf(s0.x * 5.f) + __expf(s1.x * 5.f) + __expf(s2.x * 5.f) + __expf(s3.x * 5.f);
    r1a += __expf(s0.y * 5.f) + __expf(s1.y * 5.f) + __expf(s2.y * 5.f) + __expf(s3.y * 5.f);
    r2a += __expf(s0.z * 5.f) + __expf(s1.z * 5.f) + __expf(s2.z * 5.f) + __expf(s3.z * 5.f);
    r3a += __expf(s0.w * 5.f) + __expf(s1.w * 5.f) + __expf(s2.w * 5.f) + __expf(s3.w * 5.f);
  }
#pragma unroll
  for (int off = 1; off < 16; off <<= 1) {
    r0a += __shfl_xor(r0a, off, 64);
    r1a += __shfl_xor(r1a, off, 64);
    r2a += __shfl_xor(r2a, off, 64);
    r3a += __shfl_xor(r3a, off, 64);
  }
  if (m == 0) {
    int rbase = sl * BB + i0 + quad * 4;
    ttl[rbase + 0] = r0a;
    ttl[rbase + 1] = r1a;
    ttl[rbase + 2] = r2a;
    ttl[rbase + 3] = r3a;
  }
}

__global__ __launch_bounds__(1024) void k_clred(const float* __restrict__ ttl,
                                                const float* __restrict__ posdot,
                                                float* __restrict__ outp) {
  __shared__ float red[1024];
  int t = threadIdx.x;
  float a = 0.f;
  for (int idx = t; idx < 6 * BB; idx += 1024)
    a += logf(ttl[idx]) - posdot[idx] * 5.0f;
  red[t] = a;
  __syncthreads();
  for (int off = 512; off; off >>= 1) {
    if (t < off) red[t] += red[t + off];
    __syncthreads();
  }
  if (t == 0) outp[2 * BB] = red[0] * (1.f / 12288.f);  // (cl_u + cl_i)
}

__global__ __launch_bounds__(256) void k_head(const float* __restrict__ att_u,
                                              const float* __restrict__ att_i,
                                              const float* __restrict__ skills,
                                              const float* __restrict__ w1, const float* __restrict__ b1,
                                              const float* __restrict__ w2, const float* __restrict__ b2,
                                              const float* __restrict__ pw, const float* __restrict__ pb,
                                              float* __restrict__ outp) {
  __shared__ float diag[4][96], t1[4][64];
  int t = threadIdx.x;
  int w = t >> 6, lane = t & 63;
  int b = blockIdx.x * 4 + w;
  for (int j = lane; j < 96; j += 64) {
    float su = 1.f / (1.f + __expf(-att_u[(size_t)b * 96 + j]));
    float si = 1.f / (1.f + __expf(-att_i[(size_t)b * 96 + j]));
    diag[w][j] = (su - si) * skills[(size_t)b * 96 + j];
  }
  __syncthreads();
  float a = b1[lane];
#pragma unroll 8
  for (int j = 0; j < 96; ++j) a += diag[w][j] * w1[j * 64 + lane];
  t1[w][lane] = tanhf(a);
  __syncthreads();
  float h = b2[lane];
#pragma unroll 8
  for (int kk = 0; kk < 64; ++kk) h += t1[w][kk] * w2[kk * 64 + lane];
  float p0 = h * pw[lane * 2 + 0];
  float p1 = h * pw[lane * 2 + 1];
#pragma unroll
  for (int off = 32; off; off >>= 1) {
    p0 += __shfl_xor(p0, off, 64);
    p1 += __shfl_xor(p1, off, 64);
  }
  if (lane == 0) {
    float l0 = p0 + pb[0], l1 = p1 + pb[1];
    float m = fmaxf(l0, l1);
    float e0 = __expf(l0 - m), e1 = __expf(l1 - m);
    float inv = 1.f / (e0 + e1);
    outp[(size_t)b * 2 + 0] = e0 * inv;
    outp[(size_t)b * 2 + 1] = e1 * inv;
  }
}

// ---------------- launcher ----------------
extern "C" void kernel_launch(void* const* d_in, const int* in_sizes, int n_in,
                              void* d_out, int out_size, void* d_ws, size_t ws_size,
                              hipStream_t stream) {
  const float* ego    = (const float*)d_in[0];
  const float* gc_w   = (const float*)d_in[1];
  const float* gc_b   = (const float*)d_in[2];
  const float* bi_w   = (const float*)d_in[3];
  const float* bi_b   = (const float*)d_in[4];
  const float* uh_w   = (const float*)d_in[5];
  const float* uh_b   = (const float*)d_in[6];
  const float* ih_w   = (const float*)d_in[7];
  const float* ih_b   = (const float*)d_in[8];
  const float* ud_w1  = (const float*)d_in[9];
  const float* ud_b1  = (const float*)d_in[10];
  const float* ud_w2  = (const float*)d_in[11];
  const float* ud_b2  = (const float*)d_in[12];
  const float* id_w1  = (const float*)d_in[13];
  const float* id_b1  = (const float*)d_in[14];
  const float* id_w2  = (const float*)d_in[15];
  const float* id_b2  = (const float*)d_in[16];
  const float* q_w    = (const float*)d_in[17];
  const float* q_b    = (const float*)d_in[18];
  const float* k_w    = (const float*)d_in[19];
  const float* k_b    = (const float*)d_in[20];
  const float* v_w    = (const float*)d_in[21];
  const float* v_b    = (const float*)d_in[22];
  const float* dg_w1  = (const float*)d_in[23];
  const float* dg_b1  = (const float*)d_in[24];
  const float* dg_w2  = (const float*)d_in[25];
  const float* dg_b2  = (const float*)d_in[26];
  const float* pr_w   = (const float*)d_in[27];
  const float* pr_b   = (const float*)d_in[28];
  const float* adj_vals = (const float*)d_in[29];
  const float* skills = (const float*)d_in[30];
  const int* user_id  = (const int*)d_in[31];
  const int* item_id  = (const int*)d_in[32];
  const int* adj_rows = (const int*)d_in[33];
  const int* adj_cols = (const int*)d_in[34];
  float* outp = (float*)d_out;

  char* w = (char*)d_ws;
  auto alloc = [&](size_t bytes) -> char* {
    char* p = w;
    w += (bytes + 255) & ~(size_t)255;
    return p;
  };
  float* E1     = (float*)alloc((size_t)NODE_N * DD * 4);
  float* E2     = (float*)alloc((size_t)NODE_N * DD * 4);
  uint32_t* E8  = (uint32_t*)alloc((size_t)NODE_N * DD);   // fp8 mirror, 9.6MB
  unsigned short* side16 = (unsigned short*)alloc((size_t)NODE_N * DD * 2);
  unsigned short* p16    = (unsigned short*)alloc((size_t)NODE_N * DD * 2);
  uint2* sedge_r= (uint2*)alloc((size_t)NTILE * NSUB * SCAP * 8);  // dead after sort
  uint2* sedge  = (uint2*)alloc((size_t)NNZE * 8);   // row-sorted CSR
  int*   cursor = (int*)  alloc((size_t)NTILE * NSUB * 16 * 4);
  int*   out_base = (int*)alloc((size_t)(NTILE + 1) * 4);
  int*   row_start = (int*)alloc((size_t)(NODE_N + 1) * 4);
  float* posdot = (float*)alloc((size_t)6 * BB * 4);
  float* ttl    = (float*)alloc((size_t)6 * BB * 4);

  // late-phase buffers aliased onto sedge_r (dead after k_sort_t)
  char* ap = (char*)sedge_r;
  auto alias = [&](size_t bytes) -> char* {
    char* p = ap;
    ap += (bytes + 255) & ~(size_t)255;
    return p;
  };
  float* ue     = (float*)alias((size_t)BB * 64 * 4);
  float* ie     = (float*)alias((size_t)BB * 64 * 4);
  float* recs_u = (float*)alias((size_t)NLV * BB * 32 * 4);
  float* recs_i = (float*)alias((size_t)NLV * BB * 32 * 4);
  float* att_u  = (float*)alias((size_t)BB * 96 * 4);
  float* att_i  = (float*)alias((size_t)BB * 96 * 4);
  unsigned short* n1b = (unsigned short*)alias((size_t)6 * BB * 32 * 2);
  unsigned short* n2b = (unsigned short*)alias((size_t)6 * BB * 32 * 2);

  // host-side: kc = jax.random.split(jax.random.key(42), 2)
  uint32_t a0 = 0, a1 = 2, b0 = 1, b1 = 3;
  tf_block(0u, 42u, a0, a1);
  tf_block(0u, 42u, b0, b1);
  uint32_t ku0 = a0, ku1 = b0;   // kc[0] -> u side
  uint32_t ki0 = a1, ki1 = b1;   // kc[1] -> i side

  (void)hipMemsetAsync(cursor, 0, (size_t)NTILE * NSUB * 16 * 4, stream);

  k_init<<<9375, 256, 0, stream>>>(ego, E8);
  k_scatter_t<<<(NNZE + EPB - 1) / EPB, 256, 0, stream>>>(adj_rows, adj_cols, adj_vals,
                                                          cursor, sedge_r);
  k_scan586<<<1, 1024, 0, stream>>>(cursor, out_base, row_start);
  k_sort_t<<<NTILE, 256, 0, stream>>>(sedge_r, cursor, out_base, sedge, row_start);

  float* Ebufs[2] = {E1, E2};
  for (int l = 0; l < 2; ++l) {
    k_spmm<<<37500, 256, 0, stream>>>(E8, sedge, row_start, side16, p16);
    k_transform<<<1172, 256, 0, stream>>>(gc_w + l * 4096, gc_b + l * 64,
                                          bi_w + l * 4096, bi_b + l * 64,
                                          side16, p16, Ebufs[l], (unsigned char*)E8);
  }

  k_gather<<<4096, 128, 0, stream>>>(ego, E1, E2, user_id, item_id, ue, ie);

  dim3 ge(128, 3, 2);
  k_encoder2<<<ge, 256, 0, stream>>>(ue, ie,
                                     uh_w, uh_b, ud_w1, ud_b1, ud_w2, ud_b2,
                                     ih_w, ih_b, id_w1, id_b1, id_w2, id_b2,
                                     recs_u, recs_i);

  k_attn<<<512, 256, 0, stream>>>(recs_u, q_w, q_b, k_w, k_b, v_w, v_b, att_u);
  k_attn<<<512, 256, 0, stream>>>(recs_i, q_w, q_b, k_w, k_b, v_w, v_b, att_i);

  k_noise<<<3072, 256, 0, stream>>>(att_u, att_i, ku0, ku1, ki0, ki1, n1b, n2b, posdot);

  k_ttl<<<384, 256, 0, stream>>>(n1b, n2b, ttl);
  k_clred<<<1, 1024, 0, stream>>>(ttl, posdot, outp);

  k_head<<<1024, 256, 0, stream>>>(att_u, att_i, skills, dg_w1, dg_b1, dg_w2, dg_b2,
                                   pr_w, pr_b, outp);
}